// Round 1
// baseline (248.374 us; speedup 1.0000x reference)
//
#include <hip/hip_runtime.h>
#include <math.h>

// SGC: out = log_softmax((A_hat^2 x) W + b), A_hat = D^-1/2 (A+I) D^-1/2
// (A^2 X) W == A^2 (X W): propagate in 40-dim class space.
// Z = D^-1/2 Y: Z' = di^2 (sum_s Z_s + Z_i) -> pure gather-add.
// Gathered Z buffers bf16 (80 B rows = 2 lines/edge, 8 MB footprint).
// Round-9: gemm_k rewritten barrier-free. Old version (256-node LDS tile,
// 2 syncthreads x 4 chunks, 53.7KB LDS -> 2 blocks/CU, 391-block grid)
// was latency-bound: VALUBusy 22%, HBM 9%, dur 46us vs ~10us roofline.
// New: 1 thread = 1 node, acc[40] in VGPRs (full unroll -> static idx),
// W via wave-uniform scalar loads (s_load, SMEM pipe), x as 64B/line
// float4 reads, no LDS, no barriers. prop_k / build passes verbatim.

#define FDIM 128
#define CDIM 40
#define C4   10
#define BKT_SHIFT 8
#define NB   512   // bucket slots (>= ceil(N/256))
#define NBLK 512   // edge-partition blocks
#define NPB  51    // nodes per 256-thread prop block (5 lanes/node)

// ---------- bf16 helpers (RTNE pack; finite inputs) ----------
__device__ __forceinline__ unsigned int bf16rn(float f) {
    unsigned int u = __float_as_uint(f);
    return (u + 0x7fffu + ((u >> 16) & 1u)) >> 16;
}
__device__ __forceinline__ unsigned int pack2(float lo, float hi) {
    unsigned int a = bf16rn(lo);
    unsigned int b = __float_as_uint(hi);
    b = (b + 0x7fffu + ((b >> 16) & 1u)) & 0xffff0000u;
    return a | b;
}
__device__ __forceinline__ void addu4(uint4 u, float* a) {
    a[0] += __uint_as_float(u.x << 16);
    a[1] += __uint_as_float(u.x & 0xffff0000u);
    a[2] += __uint_as_float(u.y << 16);
    a[3] += __uint_as_float(u.y & 0xffff0000u);
    a[4] += __uint_as_float(u.z << 16);
    a[5] += __uint_as_float(u.z & 0xffff0000u);
    a[6] += __uint_as_float(u.w << 16);
    a[7] += __uint_as_float(u.w & 0xffff0000u);
}

// ---- pass 1: per-block histogram over dst buckets (LDS, no global atomics)
__global__ void hist_k(const int* __restrict__ dst, int* __restrict__ G,
                       int E, int EB) {
    __shared__ int h[NB];
    int t = threadIdx.x;
    for (int i = t; i < NB; i += 256) h[i] = 0;
    __syncthreads();
    int s = blockIdx.x * EB;
    int e = min(s + EB, E);
    for (int i = s + t; i < e; i += 256)
        atomicAdd(&h[dst[i] >> BKT_SHIFT], 1);
    __syncthreads();
    for (int i = t; i < NB; i += 256) G[blockIdx.x * NB + i] = h[i];
}

// ---- pass 2: per-bucket exclusive scan over blocks (in-place on G); totals->T
__global__ void colscan_k(int* __restrict__ G, int* __restrict__ T) {
    __shared__ int lds[256];
    int j = blockIdx.x;
    int t = threadIdx.x;
    int v0 = G[(2 * t) * NB + j];
    int v1 = G[(2 * t + 1) * NB + j];
    int s = v0 + v1;
    lds[t] = s;
    __syncthreads();
    for (int off = 1; off < 256; off <<= 1) {
        int a = (t >= off) ? lds[t - off] : 0;
        __syncthreads();
        lds[t] += a;
        __syncthreads();
    }
    int excl = lds[t] - s;
    G[(2 * t) * NB + j] = excl;
    G[(2 * t + 1) * NB + j] = excl + v0;
    if (t == 255) T[j] = lds[255];
}

// ---- pass 2b: exclusive scan of bucket totals -> bs[0..NB], bs[NB]=E
__global__ void bscan_k(const int* __restrict__ T, int* __restrict__ bs) {
    __shared__ int lds[256];
    int t = threadIdx.x;
    int v0 = T[2 * t];
    int v1 = T[2 * t + 1];
    int s = v0 + v1;
    lds[t] = s;
    __syncthreads();
    for (int off = 1; off < 256; off <<= 1) {
        int a = (t >= off) ? lds[t - off] : 0;
        __syncthreads();
        lds[t] += a;
        __syncthreads();
    }
    int excl = lds[t] - s;
    bs[2 * t] = excl;
    bs[2 * t + 1] = excl + v0;
    if (t == 255) bs[NB] = lds[255];
}

// ---- pass 3: scatter packed edges into bucket-partitioned tmp
// pack: src (24 bits) | dstLocal (8 bits) << 24   [requires N < 2^24]
__global__ void part_k(const int* __restrict__ src, const int* __restrict__ dst,
                       const int* __restrict__ G, const int* __restrict__ bs,
                       unsigned int* __restrict__ tmp, int E, int EB) {
    __shared__ int offs[NB];
    __shared__ int cur[NB];
    int t = threadIdx.x;
    for (int i = t; i < NB; i += 256) {
        offs[i] = bs[i] + G[blockIdx.x * NB + i];
        cur[i] = 0;
    }
    __syncthreads();
    int s = blockIdx.x * EB;
    int e = min(s + EB, E);
    for (int i = s + t; i < e; i += 256) {
        int d = dst[i];
        int j = d >> BKT_SHIFT;
        int r = atomicAdd(&cur[j], 1);
        tmp[offs[j] + r] = (unsigned int)src[i] | ((unsigned int)(d & 255) << 24);
    }
}

// ---- pass 4: one block per bucket: rowptr/dinv/dsq + CSR col fill (all local)
__global__ void csr_k(const unsigned int* __restrict__ tmp, const int* __restrict__ bs,
                      int* __restrict__ rowptr, float* __restrict__ dinv,
                      float* __restrict__ dsq, int* __restrict__ col, int N, int E) {
    __shared__ int cnt[256];
    __shared__ int ptr[256];
    int j = blockIdx.x;
    int t = threadIdx.x;
    int base = j << BKT_SHIFT;
    int s = bs[j];
    int e = bs[j + 1];
    cnt[t] = 0;
    __syncthreads();
    for (int i = s + t; i < e; i += 256)
        atomicAdd(&cnt[tmp[i] >> 24], 1);
    __syncthreads();
    int v = cnt[t];
    ptr[t] = v;
    __syncthreads();
    for (int off = 1; off < 256; off <<= 1) {
        int a = (t >= off) ? ptr[t - off] : 0;
        __syncthreads();
        ptr[t] += a;
        __syncthreads();
    }
    int excl = ptr[t] - v;
    int node = base + t;
    if (node < N) {
        rowptr[node] = s + excl;
        float d = (float)(v + 1);              // +1 self-loop
        dinv[node] = rsqrtf(d);
        dsq[node] = sqrtf(d);
    }
    if (j == 0 && t == 0) rowptr[N] = E;
    cnt[t] = excl;  // cursor
    __syncthreads();
    for (int i = s + t; i < e; i += 256) {
        unsigned int p = tmp[i];
        int loc = p >> 24;
        int r = atomicAdd(&cnt[loc], 1);
        col[s + r] = (int)(p & 0xFFFFFF);
    }
}

// ---- Z0[node][40] (bf16) = dinv[node] * (x[node] @ W)
// ROUND-9: barrier-free, LDS-free. One thread per node; acc[40] in VGPRs
// (all loops fully unrolled -> static indexing, no scratch). W addresses are
// wave-uniform -> compiler emits scalar loads on the SMEM pipe (no VALU/LDS
// cost). x row read as 4 x float4 (one 64B line) per chunk, 4 loads in
// flight to cover HBM latency at the 1.5-wave/SIMD grid.
__global__ __launch_bounds__(256) void gemm_k(const float* __restrict__ x,
                                              const float* __restrict__ W,
                                              const float* __restrict__ dinv,
                                              uint4* __restrict__ Zbf, int n) {
    int node = blockIdx.x * 256 + threadIdx.x;
    if (node >= n) return;
    float acc[CDIM];
    #pragma unroll
    for (int c = 0; c < CDIM; ++c) acc[c] = 0.f;
    const float4* xr = (const float4*)(x + (size_t)node * FDIM);
    for (int ch = 0; ch < 8; ++ch) {   // 8 chunks of 16 features
        float4 xv0 = xr[ch * 4 + 0];
        float4 xv1 = xr[ch * 4 + 1];
        float4 xv2 = xr[ch * 4 + 2];
        float4 xv3 = xr[ch * 4 + 3];
        const float* wb = W + ch * 16 * CDIM;
        const float xs[16] = {xv0.x, xv0.y, xv0.z, xv0.w,
                              xv1.x, xv1.y, xv1.z, xv1.w,
                              xv2.x, xv2.y, xv2.z, xv2.w,
                              xv3.x, xv3.y, xv3.z, xv3.w};
        #pragma unroll
        for (int f = 0; f < 16; ++f) {
            float s = xs[f];
            const float* wr = wb + f * CDIM;
            #pragma unroll
            for (int c = 0; c < CDIM; ++c)
                acc[c] += s * wr[c];
        }
    }
    float di = dinv[node];
    uint4* zp = Zbf + (size_t)node * 5;
    #pragma unroll
    for (int g = 0; g < 5; ++g) {
        uint4 o;
        o.x = pack2(acc[g * 8 + 0] * di, acc[g * 8 + 1] * di);
        o.y = pack2(acc[g * 8 + 2] * di, acc[g * 8 + 3] * di);
        o.z = pack2(acc[g * 8 + 4] * di, acc[g * 8 + 5] * di);
        o.w = pack2(acc[g * 8 + 6] * di, acc[g * 8 + 7] * di);
        zp[g] = o;
    }
}

// ---- one hop: acc = sum_{s->i} Zin[s] + Zin[i]; Zout = di^2 * acc.
// FINAL: fuse logits = Z2*dsq + b and log_softmax, write fp32 d_out.
// 5 lanes/node x uint4 (8 bf16); 51 nodes per 256-thread block.
template <bool FINAL>
__global__ __launch_bounds__(256) void prop_k(const int* __restrict__ rowptr,
                                              const int* __restrict__ col,
                                              const float* __restrict__ dinv,
                                              const float* __restrict__ dsq,
                                              const float* __restrict__ bias,
                                              const uint4* __restrict__ Zin,
                                              uint4* __restrict__ Zout_bf,
                                              float* __restrict__ out_f32, int n) {
    __shared__ float bsm[CDIM];
    __shared__ float red[256];
    int t = threadIdx.x;
    if (FINAL && t < CDIM) bsm[t] = bias[t];
    int g = t / 5;
    int c8 = t - g * 5;
    int node = blockIdx.x * NPB + g;
    bool active = (g < NPB) && (node < n);
    float acc[8];
    #pragma unroll
    for (int c = 0; c < 8; ++c) acc[c] = 0.f;
    float w = 0.f;
    if (active) {
        float di = dinv[node];
        w = di * di;
        addu4(Zin[(size_t)node * 5 + c8], acc);   // self-loop
        int e = rowptr[node];
        int end = rowptr[node + 1];
        for (; e + 3 < end; e += 4) {
            int s0 = col[e], s1 = col[e + 1], s2 = col[e + 2], s3 = col[e + 3];
            uint4 a0 = Zin[(size_t)s0 * 5 + c8];
            uint4 a1 = Zin[(size_t)s1 * 5 + c8];
            uint4 a2 = Zin[(size_t)s2 * 5 + c8];
            uint4 a3 = Zin[(size_t)s3 * 5 + c8];
            addu4(a0, acc); addu4(a1, acc); addu4(a2, acc); addu4(a3, acc);
        }
        for (; e < end; ++e)
            addu4(Zin[(size_t)col[e] * 5 + c8], acc);
    }

    if (!FINAL) {
        if (active) {
            uint4 o;
            o.x = pack2(acc[0] * w, acc[1] * w);
            o.y = pack2(acc[2] * w, acc[3] * w);
            o.z = pack2(acc[4] * w, acc[5] * w);
            o.w = pack2(acc[6] * w, acc[7] * w);
            Zout_bf[(size_t)node * 5 + c8] = o;
        }
        return;
    }

    // FINAL: logits + log_softmax via 5-lane LDS reduction.
    __syncthreads();  // bsm ready
    float v[8];
    float m8 = -INFINITY;
    if (active) {
        float ws_ = w * dsq[node];
        #pragma unroll
        for (int j = 0; j < 8; ++j) {
            v[j] = acc[j] * ws_ + bsm[c8 * 8 + j];
            m8 = fmaxf(m8, v[j]);
        }
    }
    red[t] = m8;
    __syncthreads();
    float m = m8;
    if (active) {
        int rb = g * 5;
        m = fmaxf(fmaxf(fmaxf(red[rb], red[rb + 1]), fmaxf(red[rb + 2], red[rb + 3])),
                  red[rb + 4]);
    }
    float s8 = 0.f;
    if (active) {
        #pragma unroll
        for (int j = 0; j < 8; ++j) s8 += expf(v[j] - m);
    }
    __syncthreads();
    red[t] = s8;
    __syncthreads();
    if (active) {
        int rb = g * 5;
        float s = (red[rb] + red[rb + 1]) + (red[rb + 2] + red[rb + 3]) + red[rb + 4];
        float ls = m + logf(s);
        float* p = out_f32 + (size_t)node * CDIM + c8 * 8;
        *(float4*)p = make_float4(v[0] - ls, v[1] - ls, v[2] - ls, v[3] - ls);
        *(float4*)(p + 4) = make_float4(v[4] - ls, v[5] - ls, v[6] - ls, v[7] - ls);
    }
}

extern "C" void kernel_launch(void* const* d_in, const int* in_sizes, int n_in,
                              void* d_out, int out_size, void* d_ws, size_t ws_size,
                              hipStream_t stream) {
    const float* x = (const float*)d_in[0];
    const float* W = (const float*)d_in[1];
    const float* b = (const float*)d_in[2];
    const int* ei = (const int*)d_in[3];

    int C = in_sizes[2];            // 40
    int F = in_sizes[1] / C;        // 128
    int N = in_sizes[0] / F;        // 100000
    int E = in_sizes[3] / 2;        // 1600000
    const int* src = ei;
    const int* dst = ei + E;

    // workspace: union region holds {G,T,bs,tmp} during build, then Z0bf (8MB).
    // Zb (hop-1 bf16 out, 8MB) separate: hop-2 gathers from it while writing
    // d_out, so it must not alias d_out.
    char* ws = (char*)d_ws;
    size_t goff = 0;
    int* G = (int*)(ws + goff);                       goff += (size_t)NBLK * NB * 4;
    int* T = (int*)(ws + goff);                       goff += (size_t)NB * 4;
    int* bs = (int*)(ws + goff);                      goff += (size_t)(NB + 1) * 4 + 12;
    goff = (goff + 15) & ~(size_t)15;
    unsigned int* tmp = (unsigned int*)(ws + goff);   goff += (size_t)E * 4;
    size_t z0bytes = (size_t)N * 80;                  // 5 x uint4 per node
    size_t unionEnd = (z0bytes > goff) ? z0bytes : goff;
    unionEnd = (unionEnd + 15) & ~(size_t)15;
    uint4* Z0bf = (uint4*)ws;        // overlays build scratch
    size_t off = unionEnd;
    int* rowptr = (int*)(ws + off); off += ((size_t)(N + 1) * 4 + 15) & ~(size_t)15;
    float* dinv = (float*)(ws + off); off += ((size_t)N * 4 + 15) & ~(size_t)15;
    float* dsq = (float*)(ws + off); off += ((size_t)N * 4 + 15) & ~(size_t)15;
    int* col = (int*)(ws + off); off += ((size_t)E * 4 + 15) & ~(size_t)15;
    uint4* Zb = (uint4*)(ws + off); off += (z0bytes + 15) & ~(size_t)15;

    int EB = (E + NBLK - 1) / NBLK;
    int NBr = (N + 255) >> BKT_SHIFT;

    hist_k<<<NBLK, 256, 0, stream>>>(dst, G, E, EB);
    colscan_k<<<NB, 256, 0, stream>>>(G, T);
    bscan_k<<<1, 256, 0, stream>>>(T, bs);
    part_k<<<NBLK, 256, 0, stream>>>(src, dst, G, bs, tmp, E, EB);
    csr_k<<<NBr, 256, 0, stream>>>(tmp, bs, rowptr, dinv, dsq, col, N, E);

    gemm_k<<<(N + 255) / 256, 256, 0, stream>>>(x, W, dinv, Z0bf, N);

    int pgrid = (N + NPB - 1) / NPB;
    prop_k<false><<<pgrid, 256, 0, stream>>>(rowptr, col, dinv, dsq, b,
                                             Z0bf, Zb, nullptr, N);
    prop_k<true><<<pgrid, 256, 0, stream>>>(rowptr, col, dinv, dsq, b,
                                            Zb, nullptr, (float*)d_out, N);
}

// Round 2
// 233.591 us; speedup vs baseline: 1.0633x; 1.0633x over previous
//
#include <hip/hip_runtime.h>
#include <math.h>

// SGC: out = log_softmax((A_hat^2 x) W + b), A_hat = D^-1/2 (A+I) D^-1/2
// (A^2 X) W == A^2 (X W): propagate in 40-dim class space.
// Z = D^-1/2 Y: Z' = di^2 (sum_s Z_s + Z_i) -> pure gather-add.
// Gathered Z buffers bf16 (80 B rows = 2 lines/edge, 8 MB footprint).
// Round-10: gemm_k redesigned for occupancy + register safety.
// Round-9 (1 thread/node, acc[40]) spilled: VGPR_Count=32 < 40 accumulators
// -> scratch round-trips, VALUBusy 10%, 55-67us. Root causes: acc too big,
// grid 391 waves-starved (1.5 waves/SIMD), serialized load chain.
// New: 320 thr = 5 waves/block; wave w owns class-group w (8 classes) ->
// cg is readfirstlane-uniform -> W reads are s_load (scalar pipe, free).
// 64 nodes/block staged transposed in 32KB LDS (both store & load lane-
// consecutive = conflict-free), ONE barrier. acc[8] -> ~30 VGPR.
// Grid 1563, 5 blocks/CU by LDS -> ~25 waves/CU. prop_k / build verbatim.

#define FDIM 128
#define CDIM 40
#define C4   10
#define BKT_SHIFT 8
#define NB   512   // bucket slots (>= ceil(N/256))
#define NBLK 512   // edge-partition blocks
#define NPB  51    // nodes per 256-thread prop block (5 lanes/node)

// ---------- bf16 helpers (RTNE pack; finite inputs) ----------
__device__ __forceinline__ unsigned int bf16rn(float f) {
    unsigned int u = __float_as_uint(f);
    return (u + 0x7fffu + ((u >> 16) & 1u)) >> 16;
}
__device__ __forceinline__ unsigned int pack2(float lo, float hi) {
    unsigned int a = bf16rn(lo);
    unsigned int b = __float_as_uint(hi);
    b = (b + 0x7fffu + ((b >> 16) & 1u)) & 0xffff0000u;
    return a | b;
}
__device__ __forceinline__ void addu4(uint4 u, float* a) {
    a[0] += __uint_as_float(u.x << 16);
    a[1] += __uint_as_float(u.x & 0xffff0000u);
    a[2] += __uint_as_float(u.y << 16);
    a[3] += __uint_as_float(u.y & 0xffff0000u);
    a[4] += __uint_as_float(u.z << 16);
    a[5] += __uint_as_float(u.z & 0xffff0000u);
    a[6] += __uint_as_float(u.w << 16);
    a[7] += __uint_as_float(u.w & 0xffff0000u);
}

// ---- pass 1: per-block histogram over dst buckets (LDS, no global atomics)
__global__ void hist_k(const int* __restrict__ dst, int* __restrict__ G,
                       int E, int EB) {
    __shared__ int h[NB];
    int t = threadIdx.x;
    for (int i = t; i < NB; i += 256) h[i] = 0;
    __syncthreads();
    int s = blockIdx.x * EB;
    int e = min(s + EB, E);
    for (int i = s + t; i < e; i += 256)
        atomicAdd(&h[dst[i] >> BKT_SHIFT], 1);
    __syncthreads();
    for (int i = t; i < NB; i += 256) G[blockIdx.x * NB + i] = h[i];
}

// ---- pass 2: per-bucket exclusive scan over blocks (in-place on G); totals->T
__global__ void colscan_k(int* __restrict__ G, int* __restrict__ T) {
    __shared__ int lds[256];
    int j = blockIdx.x;
    int t = threadIdx.x;
    int v0 = G[(2 * t) * NB + j];
    int v1 = G[(2 * t + 1) * NB + j];
    int s = v0 + v1;
    lds[t] = s;
    __syncthreads();
    for (int off = 1; off < 256; off <<= 1) {
        int a = (t >= off) ? lds[t - off] : 0;
        __syncthreads();
        lds[t] += a;
        __syncthreads();
    }
    int excl = lds[t] - s;
    G[(2 * t) * NB + j] = excl;
    G[(2 * t + 1) * NB + j] = excl + v0;
    if (t == 255) T[j] = lds[255];
}

// ---- pass 2b: exclusive scan of bucket totals -> bs[0..NB], bs[NB]=E
__global__ void bscan_k(const int* __restrict__ T, int* __restrict__ bs) {
    __shared__ int lds[256];
    int t = threadIdx.x;
    int v0 = T[2 * t];
    int v1 = T[2 * t + 1];
    int s = v0 + v1;
    lds[t] = s;
    __syncthreads();
    for (int off = 1; off < 256; off <<= 1) {
        int a = (t >= off) ? lds[t - off] : 0;
        __syncthreads();
        lds[t] += a;
        __syncthreads();
    }
    int excl = lds[t] - s;
    bs[2 * t] = excl;
    bs[2 * t + 1] = excl + v0;
    if (t == 255) bs[NB] = lds[255];
}

// ---- pass 3: scatter packed edges into bucket-partitioned tmp
// pack: src (24 bits) | dstLocal (8 bits) << 24   [requires N < 2^24]
__global__ void part_k(const int* __restrict__ src, const int* __restrict__ dst,
                       const int* __restrict__ G, const int* __restrict__ bs,
                       unsigned int* __restrict__ tmp, int E, int EB) {
    __shared__ int offs[NB];
    __shared__ int cur[NB];
    int t = threadIdx.x;
    for (int i = t; i < NB; i += 256) {
        offs[i] = bs[i] + G[blockIdx.x * NB + i];
        cur[i] = 0;
    }
    __syncthreads();
    int s = blockIdx.x * EB;
    int e = min(s + EB, E);
    for (int i = s + t; i < e; i += 256) {
        int d = dst[i];
        int j = d >> BKT_SHIFT;
        int r = atomicAdd(&cur[j], 1);
        tmp[offs[j] + r] = (unsigned int)src[i] | ((unsigned int)(d & 255) << 24);
    }
}

// ---- pass 4: one block per bucket: rowptr/dinv/dsq + CSR col fill (all local)
__global__ void csr_k(const unsigned int* __restrict__ tmp, const int* __restrict__ bs,
                      int* __restrict__ rowptr, float* __restrict__ dinv,
                      float* __restrict__ dsq, int* __restrict__ col, int N, int E) {
    __shared__ int cnt[256];
    __shared__ int ptr[256];
    int j = blockIdx.x;
    int t = threadIdx.x;
    int base = j << BKT_SHIFT;
    int s = bs[j];
    int e = bs[j + 1];
    cnt[t] = 0;
    __syncthreads();
    for (int i = s + t; i < e; i += 256)
        atomicAdd(&cnt[tmp[i] >> 24], 1);
    __syncthreads();
    int v = cnt[t];
    ptr[t] = v;
    __syncthreads();
    for (int off = 1; off < 256; off <<= 1) {
        int a = (t >= off) ? ptr[t - off] : 0;
        __syncthreads();
        ptr[t] += a;
        __syncthreads();
    }
    int excl = ptr[t] - v;
    int node = base + t;
    if (node < N) {
        rowptr[node] = s + excl;
        float d = (float)(v + 1);              // +1 self-loop
        dinv[node] = rsqrtf(d);
        dsq[node] = sqrtf(d);
    }
    if (j == 0 && t == 0) rowptr[N] = E;
    cnt[t] = excl;  // cursor
    __syncthreads();
    for (int i = s + t; i < e; i += 256) {
        unsigned int p = tmp[i];
        int loc = p >> 24;
        int r = atomicAdd(&cnt[loc], 1);
        col[s + r] = (int)(p & 0xFFFFFF);
    }
}

// ---- Z0[node][40] (bf16) = dinv[node] * (x[node] @ W)
// ROUND-10: wave-per-class-group. 320 threads = 5 waves; wave w computes
// classes [8w, 8w+8) for the block's 64 nodes. W addresses are wave-uniform
// (readfirstlane) -> s_load_dwordx4 on the scalar pipe. x staged transposed
// xT[f][node] (32 KB): stores AND loads are lane-consecutive -> zero bank
// conflicts. One barrier. acc[8] statically indexed -> stays in VGPRs.
__global__ __launch_bounds__(320) void gemm_k(const float* __restrict__ x,
                                              const float* __restrict__ W,
                                              const float* __restrict__ dinv,
                                              uint4* __restrict__ Zbf, int n) {
    __shared__ float xT[FDIM][64];   // 32 KB, [feature][node-local]
    int t = threadIdx.x;
    int base = blockIdx.x * 64;
    // stage: i enumerates (f4, node-local); node-local = i&63 so each wave's
    // 64 lanes hit consecutive LDS words (conflict-free). Global reads are
    // stride-512B per instruction but every 64B line is fully consumed.
    for (int i = t; i < 2048; i += 320) {
        int nl = i & 63;
        int f4 = i >> 6;
        int node = base + nl;
        float4 xv = make_float4(0.f, 0.f, 0.f, 0.f);
        if (node < n) xv = *(const float4*)(x + (size_t)node * FDIM + f4 * 4);
        xT[f4 * 4 + 0][nl] = xv.x;
        xT[f4 * 4 + 1][nl] = xv.y;
        xT[f4 * 4 + 2][nl] = xv.z;
        xT[f4 * 4 + 3][nl] = xv.w;
    }
    int cg = __builtin_amdgcn_readfirstlane(t >> 6);  // 0..4, wave-uniform
    int ng = t & 63;
    float acc[8];
    #pragma unroll
    for (int c = 0; c < 8; ++c) acc[c] = 0.f;
    __syncthreads();
    const float* wbase = W + cg * 8;   // uniform -> scalar loads
    #pragma unroll 4
    for (int f = 0; f < FDIM; ++f) {
        float xv = xT[f][ng];
        float4 w0 = *(const float4*)(wbase + f * CDIM);      // s_load_dwordx4
        float4 w1 = *(const float4*)(wbase + f * CDIM + 4);  // s_load_dwordx4
        acc[0] += xv * w0.x; acc[1] += xv * w0.y;
        acc[2] += xv * w0.z; acc[3] += xv * w0.w;
        acc[4] += xv * w1.x; acc[5] += xv * w1.y;
        acc[6] += xv * w1.z; acc[7] += xv * w1.w;
    }
    int node = base + ng;
    if (node < n) {
        float di = dinv[node];
        uint4 o;
        o.x = pack2(acc[0] * di, acc[1] * di);
        o.y = pack2(acc[2] * di, acc[3] * di);
        o.z = pack2(acc[4] * di, acc[5] * di);
        o.w = pack2(acc[6] * di, acc[7] * di);
        Zbf[(size_t)node * 5 + cg] = o;
    }
}

// ---- one hop: acc = sum_{s->i} Zin[s] + Zin[i]; Zout = di^2 * acc.
// FINAL: fuse logits = Z2*dsq + b and log_softmax, write fp32 d_out.
// 5 lanes/node x uint4 (8 bf16); 51 nodes per 256-thread block.
template <bool FINAL>
__global__ __launch_bounds__(256) void prop_k(const int* __restrict__ rowptr,
                                              const int* __restrict__ col,
                                              const float* __restrict__ dinv,
                                              const float* __restrict__ dsq,
                                              const float* __restrict__ bias,
                                              const uint4* __restrict__ Zin,
                                              uint4* __restrict__ Zout_bf,
                                              float* __restrict__ out_f32, int n) {
    __shared__ float bsm[CDIM];
    __shared__ float red[256];
    int t = threadIdx.x;
    if (FINAL && t < CDIM) bsm[t] = bias[t];
    int g = t / 5;
    int c8 = t - g * 5;
    int node = blockIdx.x * NPB + g;
    bool active = (g < NPB) && (node < n);
    float acc[8];
    #pragma unroll
    for (int c = 0; c < 8; ++c) acc[c] = 0.f;
    float w = 0.f;
    if (active) {
        float di = dinv[node];
        w = di * di;
        addu4(Zin[(size_t)node * 5 + c8], acc);   // self-loop
        int e = rowptr[node];
        int end = rowptr[node + 1];
        for (; e + 3 < end; e += 4) {
            int s0 = col[e], s1 = col[e + 1], s2 = col[e + 2], s3 = col[e + 3];
            uint4 a0 = Zin[(size_t)s0 * 5 + c8];
            uint4 a1 = Zin[(size_t)s1 * 5 + c8];
            uint4 a2 = Zin[(size_t)s2 * 5 + c8];
            uint4 a3 = Zin[(size_t)s3 * 5 + c8];
            addu4(a0, acc); addu4(a1, acc); addu4(a2, acc); addu4(a3, acc);
        }
        for (; e < end; ++e)
            addu4(Zin[(size_t)col[e] * 5 + c8], acc);
    }

    if (!FINAL) {
        if (active) {
            uint4 o;
            o.x = pack2(acc[0] * w, acc[1] * w);
            o.y = pack2(acc[2] * w, acc[3] * w);
            o.z = pack2(acc[4] * w, acc[5] * w);
            o.w = pack2(acc[6] * w, acc[7] * w);
            Zout_bf[(size_t)node * 5 + c8] = o;
        }
        return;
    }

    // FINAL: logits + log_softmax via 5-lane LDS reduction.
    __syncthreads();  // bsm ready
    float v[8];
    float m8 = -INFINITY;
    if (active) {
        float ws_ = w * dsq[node];
        #pragma unroll
        for (int j = 0; j < 8; ++j) {
            v[j] = acc[j] * ws_ + bsm[c8 * 8 + j];
            m8 = fmaxf(m8, v[j]);
        }
    }
    red[t] = m8;
    __syncthreads();
    float m = m8;
    if (active) {
        int rb = g * 5;
        m = fmaxf(fmaxf(fmaxf(red[rb], red[rb + 1]), fmaxf(red[rb + 2], red[rb + 3])),
                  red[rb + 4]);
    }
    float s8 = 0.f;
    if (active) {
        #pragma unroll
        for (int j = 0; j < 8; ++j) s8 += expf(v[j] - m);
    }
    __syncthreads();
    red[t] = s8;
    __syncthreads();
    if (active) {
        int rb = g * 5;
        float s = (red[rb] + red[rb + 1]) + (red[rb + 2] + red[rb + 3]) + red[rb + 4];
        float ls = m + logf(s);
        float* p = out_f32 + (size_t)node * CDIM + c8 * 8;
        *(float4*)p = make_float4(v[0] - ls, v[1] - ls, v[2] - ls, v[3] - ls);
        *(float4*)(p + 4) = make_float4(v[4] - ls, v[5] - ls, v[6] - ls, v[7] - ls);
    }
}

extern "C" void kernel_launch(void* const* d_in, const int* in_sizes, int n_in,
                              void* d_out, int out_size, void* d_ws, size_t ws_size,
                              hipStream_t stream) {
    const float* x = (const float*)d_in[0];
    const float* W = (const float*)d_in[1];
    const float* b = (const float*)d_in[2];
    const int* ei = (const int*)d_in[3];

    int C = in_sizes[2];            // 40
    int F = in_sizes[1] / C;        // 128
    int N = in_sizes[0] / F;        // 100000
    int E = in_sizes[3] / 2;        // 1600000
    const int* src = ei;
    const int* dst = ei + E;

    // workspace: union region holds {G,T,bs,tmp} during build, then Z0bf (8MB).
    // Zb (hop-1 bf16 out, 8MB) separate: hop-2 gathers from it while writing
    // d_out, so it must not alias d_out.
    char* ws = (char*)d_ws;
    size_t goff = 0;
    int* G = (int*)(ws + goff);                       goff += (size_t)NBLK * NB * 4;
    int* T = (int*)(ws + goff);                       goff += (size_t)NB * 4;
    int* bs = (int*)(ws + goff);                      goff += (size_t)(NB + 1) * 4 + 12;
    goff = (goff + 15) & ~(size_t)15;
    unsigned int* tmp = (unsigned int*)(ws + goff);   goff += (size_t)E * 4;
    size_t z0bytes = (size_t)N * 80;                  // 5 x uint4 per node
    size_t unionEnd = (z0bytes > goff) ? z0bytes : goff;
    unionEnd = (unionEnd + 15) & ~(size_t)15;
    uint4* Z0bf = (uint4*)ws;        // overlays build scratch
    size_t off = unionEnd;
    int* rowptr = (int*)(ws + off); off += ((size_t)(N + 1) * 4 + 15) & ~(size_t)15;
    float* dinv = (float*)(ws + off); off += ((size_t)N * 4 + 15) & ~(size_t)15;
    float* dsq = (float*)(ws + off); off += ((size_t)N * 4 + 15) & ~(size_t)15;
    int* col = (int*)(ws + off); off += ((size_t)E * 4 + 15) & ~(size_t)15;
    uint4* Zb = (uint4*)(ws + off); off += (z0bytes + 15) & ~(size_t)15;

    int EB = (E + NBLK - 1) / NBLK;
    int NBr = (N + 255) >> BKT_SHIFT;

    hist_k<<<NBLK, 256, 0, stream>>>(dst, G, E, EB);
    colscan_k<<<NB, 256, 0, stream>>>(G, T);
    bscan_k<<<1, 256, 0, stream>>>(T, bs);
    part_k<<<NBLK, 256, 0, stream>>>(src, dst, G, bs, tmp, E, EB);
    csr_k<<<NBr, 256, 0, stream>>>(tmp, bs, rowptr, dinv, dsq, col, N, E);

    gemm_k<<<(N + 63) / 64, 320, 0, stream>>>(x, W, dinv, Z0bf, N);

    int pgrid = (N + NPB - 1) / NPB;
    prop_k<false><<<pgrid, 256, 0, stream>>>(rowptr, col, dinv, dsq, b,
                                             Z0bf, Zb, nullptr, N);
    prop_k<true><<<pgrid, 256, 0, stream>>>(rowptr, col, dinv, dsq, b,
                                            Zb, nullptr, (float*)d_out, N);
}

// Round 3
// 222.143 us; speedup vs baseline: 1.1181x; 1.0515x over previous
//
#include <hip/hip_runtime.h>
#include <math.h>

// SGC: out = log_softmax((A_hat^2 x) W + b), A_hat = D^-1/2 (A+I) D^-1/2
// (A^2 X) W == A^2 (X W): propagate in 40-dim class space.
// Z = D^-1/2 Y: Z' = di^2 (sum_s Z_s + Z_i) -> pure gather-add.
// Gathered Z buffers bf16 (80 B rows = 2 lines/edge, 8 MB footprint).
// Round-11: gemm_k -> MFMA. Rounds 5/9/10 all plateaued at 42-46us: every
// fp32-VALU structure trades one stall for another (r5 DS-pipe, r9 spill,
// r10 SMEM lgkmcnt(0) drain serializing the inner loop at scalar-cache
// latency). The GEMM is 1 GFLOP -> ~free on matrix cores. New gemm_k:
// wave = 16 nodes x 40 classes (3 N-tiles), mfma_f32_16x16x32_bf16,
// split-bf16 inputs (x=xh+xl, W=Wh+Wl; 3 MFMAs hh+lh+hl, rel err ~2^-15,
// 7x below existing bf16 Z-store quantization -> absmax unchanged).
// A frags load STRAIGHT from global x (16 rows x 64B contiguous per
// instr = coalesced, no LDS, no barrier); W frags pre-swizzled once by
// wprep_k into fragment-order hi/lo uint4 arrays (24KB, L2-hot).
// LDS only for the epilogue transpose (13KB). prop_k / build verbatim.

#define FDIM 128
#define CDIM 40
#define C4   10
#define BKT_SHIFT 8
#define NB   512   // bucket slots (>= ceil(N/256))
#define NBLK 512   // edge-partition blocks
#define NPB  51    // nodes per 256-thread prop block (5 lanes/node)

typedef __attribute__((ext_vector_type(4))) float floatx4;
typedef __attribute__((ext_vector_type(8))) short bshort8;

// ---------- bf16 helpers (RTNE pack; finite inputs) ----------
__device__ __forceinline__ unsigned int bf16rn(float f) {
    unsigned int u = __float_as_uint(f);
    return (u + 0x7fffu + ((u >> 16) & 1u)) >> 16;
}
__device__ __forceinline__ unsigned int pack2(float lo, float hi) {
    unsigned int a = bf16rn(lo);
    unsigned int b = __float_as_uint(hi);
    b = (b + 0x7fffu + ((b >> 16) & 1u)) & 0xffff0000u;
    return a | b;
}
__device__ __forceinline__ void addu4(uint4 u, float* a) {
    a[0] += __uint_as_float(u.x << 16);
    a[1] += __uint_as_float(u.x & 0xffff0000u);
    a[2] += __uint_as_float(u.y << 16);
    a[3] += __uint_as_float(u.y & 0xffff0000u);
    a[4] += __uint_as_float(u.z << 16);
    a[5] += __uint_as_float(u.z & 0xffff0000u);
    a[6] += __uint_as_float(u.w << 16);
    a[7] += __uint_as_float(u.w & 0xffff0000u);
}

// ---- pass 1: per-block histogram over dst buckets (LDS, no global atomics)
__global__ void hist_k(const int* __restrict__ dst, int* __restrict__ G,
                       int E, int EB) {
    __shared__ int h[NB];
    int t = threadIdx.x;
    for (int i = t; i < NB; i += 256) h[i] = 0;
    __syncthreads();
    int s = blockIdx.x * EB;
    int e = min(s + EB, E);
    for (int i = s + t; i < e; i += 256)
        atomicAdd(&h[dst[i] >> BKT_SHIFT], 1);
    __syncthreads();
    for (int i = t; i < NB; i += 256) G[blockIdx.x * NB + i] = h[i];
}

// ---- pass 2: per-bucket exclusive scan over blocks (in-place on G); totals->T
__global__ void colscan_k(int* __restrict__ G, int* __restrict__ T) {
    __shared__ int lds[256];
    int j = blockIdx.x;
    int t = threadIdx.x;
    int v0 = G[(2 * t) * NB + j];
    int v1 = G[(2 * t + 1) * NB + j];
    int s = v0 + v1;
    lds[t] = s;
    __syncthreads();
    for (int off = 1; off < 256; off <<= 1) {
        int a = (t >= off) ? lds[t - off] : 0;
        __syncthreads();
        lds[t] += a;
        __syncthreads();
    }
    int excl = lds[t] - s;
    G[(2 * t) * NB + j] = excl;
    G[(2 * t + 1) * NB + j] = excl + v0;
    if (t == 255) T[j] = lds[255];
}

// ---- pass 2b: exclusive scan of bucket totals -> bs[0..NB], bs[NB]=E
__global__ void bscan_k(const int* __restrict__ T, int* __restrict__ bs) {
    __shared__ int lds[256];
    int t = threadIdx.x;
    int v0 = T[2 * t];
    int v1 = T[2 * t + 1];
    int s = v0 + v1;
    lds[t] = s;
    __syncthreads();
    for (int off = 1; off < 256; off <<= 1) {
        int a = (t >= off) ? lds[t - off] : 0;
        __syncthreads();
        lds[t] += a;
        __syncthreads();
    }
    int excl = lds[t] - s;
    bs[2 * t] = excl;
    bs[2 * t + 1] = excl + v0;
    if (t == 255) bs[NB] = lds[255];
}

// ---- pass 3: scatter packed edges into bucket-partitioned tmp
// pack: src (24 bits) | dstLocal (8 bits) << 24   [requires N < 2^24]
__global__ void part_k(const int* __restrict__ src, const int* __restrict__ dst,
                       const int* __restrict__ G, const int* __restrict__ bs,
                       unsigned int* __restrict__ tmp, int E, int EB) {
    __shared__ int offs[NB];
    __shared__ int cur[NB];
    int t = threadIdx.x;
    for (int i = t; i < NB; i += 256) {
        offs[i] = bs[i] + G[blockIdx.x * NB + i];
        cur[i] = 0;
    }
    __syncthreads();
    int s = blockIdx.x * EB;
    int e = min(s + EB, E);
    for (int i = s + t; i < e; i += 256) {
        int d = dst[i];
        int j = d >> BKT_SHIFT;
        int r = atomicAdd(&cur[j], 1);
        tmp[offs[j] + r] = (unsigned int)src[i] | ((unsigned int)(d & 255) << 24);
    }
}

// ---- pass 4: one block per bucket: rowptr/dinv/dsq + CSR col fill (all local)
__global__ void csr_k(const unsigned int* __restrict__ tmp, const int* __restrict__ bs,
                      int* __restrict__ rowptr, float* __restrict__ dinv,
                      float* __restrict__ dsq, int* __restrict__ col, int N, int E) {
    __shared__ int cnt[256];
    __shared__ int ptr[256];
    int j = blockIdx.x;
    int t = threadIdx.x;
    int base = j << BKT_SHIFT;
    int s = bs[j];
    int e = bs[j + 1];
    cnt[t] = 0;
    __syncthreads();
    for (int i = s + t; i < e; i += 256)
        atomicAdd(&cnt[tmp[i] >> 24], 1);
    __syncthreads();
    int v = cnt[t];
    ptr[t] = v;
    __syncthreads();
    for (int off = 1; off < 256; off <<= 1) {
        int a = (t >= off) ? ptr[t - off] : 0;
        __syncthreads();
        ptr[t] += a;
        __syncthreads();
    }
    int excl = ptr[t] - v;
    int node = base + t;
    if (node < N) {
        rowptr[node] = s + excl;
        float d = (float)(v + 1);              // +1 self-loop
        dinv[node] = rsqrtf(d);
        dsq[node] = sqrtf(d);
    }
    if (j == 0 && t == 0) rowptr[N] = E;
    cnt[t] = excl;  // cursor
    __syncthreads();
    for (int i = s + t; i < e; i += 256) {
        unsigned int p = tmp[i];
        int loc = p >> 24;
        int r = atomicAdd(&cnt[loc], 1);
        col[s + r] = (int)(p & 0xFFFFFF);
    }
}

// ---- W fragment prep (once): split-bf16 W into MFMA B-fragment order.
// B frag for mfma_f32_16x16x32_bf16: lane l holds B[k = 8*(l>>4)+j][n = l&15].
// WF[(nt*4+ch)*64 + l] = hi frag, WF[768 + ...] = lo frag (uint4 = 8 bf16).
// k_global = ch*32 + 8*(l>>4) + j ; class = nt*16 + (l&15), 0 if >= CDIM.
__global__ __launch_bounds__(256) void wprep_k(const float* __restrict__ W,
                                               uint4* __restrict__ WF) {
    int t = threadIdx.x;
    for (int s = t; s < 768; s += 256) {
        int l = s & 63;
        int g = s >> 6;           // 0..11: nt = g>>2, ch = g&3
        int nt = g >> 2;
        int ch = g & 3;
        int c = nt * 16 + (l & 15);
        int kb = ch * 32 + ((l >> 4) << 3);
        unsigned int hw[4], lw[4];
        #pragma unroll
        for (int jw = 0; jw < 4; ++jw) {
            unsigned int hs[2], ls[2];
            #pragma unroll
            for (int e = 0; e < 2; ++e) {
                int j = jw * 2 + e;
                float w = (c < CDIM) ? W[(kb + j) * CDIM + c] : 0.f;
                unsigned int u = __float_as_uint(w);
                float wh = __uint_as_float(u & 0xffff0000u);
                float wr = w - wh;
                hs[e] = u >> 16;
                ls[e] = __float_as_uint(wr) >> 16;
            }
            hw[jw] = hs[0] | (hs[1] << 16);
            lw[jw] = ls[0] | (ls[1] << 16);
        }
        WF[g * 64 + l] = make_uint4(hw[0], hw[1], hw[2], hw[3]);
        WF[768 + g * 64 + l] = make_uint4(lw[0], lw[1], lw[2], lw[3]);
    }
}

// ---- Z0[node][40] (bf16) = dinv[node] * (x[node] @ W)  -- MFMA version.
// Block = 256 thr = 4 waves; wave w owns nodes [blk*64 + 16w, +16), all 40
// classes as 3 N-tiles of 16. A frag (lane l: row l&15, k=8*(l>>4)+j) loads
// straight from global x: per instr 16 rows x 64B contiguous = coalesced.
// 3 MFMAs per (nt,ch): xh*Wh + xl*Wh + xh*Wl. Epilogue transposes D frags
// (row = 4*(l>>4)+reg, col = l&15) through 13KB LDS into packed bf16 rows.
__device__ __forceinline__ void split8(const float* p, bshort8& hi, bshort8& lo) {
    float4 a = *(const float4*)p;
    float4 b = *(const float4*)(p + 4);
    float f[8] = {a.x, a.y, a.z, a.w, b.x, b.y, b.z, b.w};
    #pragma unroll
    for (int j = 0; j < 8; ++j) {
        unsigned int u = __float_as_uint(f[j]);
        float r = f[j] - __uint_as_float(u & 0xffff0000u);
        hi[j] = (short)(u >> 16);
        lo[j] = (short)(__float_as_uint(r) >> 16);
    }
}

#define EPS 52   // epilogue LDS row stride (floats): 16B-aligned, lg 2-way only

__global__ __launch_bounds__(256) void gemm_k(const float* __restrict__ x,
                                              const uint4* __restrict__ WF,
                                              const float* __restrict__ dinv,
                                              uint4* __restrict__ Zbf, int n) {
    __shared__ float ep[64 * EPS];   // 13.3 KB
    int t = threadIdx.x;
    int wid = t >> 6;
    int l = t & 63;
    int lr = l & 15;
    int lg = l >> 4;
    int base64 = blockIdx.x * 64;
    int mbase = base64 + wid * 16;
    int node_a = mbase + lr;
    bool arow_ok = node_a < n;
    const bshort8* WFv = (const bshort8*)WF;

    floatx4 acc0 = {0.f, 0.f, 0.f, 0.f};
    floatx4 acc1 = {0.f, 0.f, 0.f, 0.f};
    floatx4 acc2 = {0.f, 0.f, 0.f, 0.f};

    #pragma unroll
    for (int ch = 0; ch < 4; ++ch) {
        bshort8 ah, al;
        if (arow_ok) {
            split8(x + (size_t)node_a * FDIM + ch * 32 + lg * 8, ah, al);
        } else {
            #pragma unroll
            for (int j = 0; j < 8; ++j) { ah[j] = 0; al[j] = 0; }
        }
        bshort8 bh0 = WFv[(0 * 4 + ch) * 64 + l];
        bshort8 bl0 = WFv[768 + (0 * 4 + ch) * 64 + l];
        bshort8 bh1 = WFv[(1 * 4 + ch) * 64 + l];
        bshort8 bl1 = WFv[768 + (1 * 4 + ch) * 64 + l];
        bshort8 bh2 = WFv[(2 * 4 + ch) * 64 + l];
        bshort8 bl2 = WFv[768 + (2 * 4 + ch) * 64 + l];
        acc0 = __builtin_amdgcn_mfma_f32_16x16x32_bf16(ah, bh0, acc0, 0, 0, 0);
        acc0 = __builtin_amdgcn_mfma_f32_16x16x32_bf16(al, bh0, acc0, 0, 0, 0);
        acc0 = __builtin_amdgcn_mfma_f32_16x16x32_bf16(ah, bl0, acc0, 0, 0, 0);
        acc1 = __builtin_amdgcn_mfma_f32_16x16x32_bf16(ah, bh1, acc1, 0, 0, 0);
        acc1 = __builtin_amdgcn_mfma_f32_16x16x32_bf16(al, bh1, acc1, 0, 0, 0);
        acc1 = __builtin_amdgcn_mfma_f32_16x16x32_bf16(ah, bl1, acc1, 0, 0, 0);
        acc2 = __builtin_amdgcn_mfma_f32_16x16x32_bf16(ah, bh2, acc2, 0, 0, 0);
        acc2 = __builtin_amdgcn_mfma_f32_16x16x32_bf16(al, bh2, acc2, 0, 0, 0);
        acc2 = __builtin_amdgcn_mfma_f32_16x16x32_bf16(ah, bl2, acc2, 0, 0, 0);
    }

    // epilogue: D lane l reg r -> node mbase + 4*lg + r, class nt*16 + lr.
    int nlb = wid * 16 + 4 * lg;
    #pragma unroll
    for (int r = 0; r < 4; ++r) {
        int nd = mbase + 4 * lg + r;
        float di = (nd < n) ? dinv[nd] : 0.f;
        ep[(nlb + r) * EPS + 0 * 16 + lr] = acc0[r] * di;
        ep[(nlb + r) * EPS + 1 * 16 + lr] = acc1[r] * di;
        ep[(nlb + r) * EPS + 2 * 16 + lr] = acc2[r] * di;
    }
    __syncthreads();
    for (int i = t; i < 320; i += 256) {
        int nl2 = i / 5;
        int cg = i - nl2 * 5;
        int node = base64 + nl2;
        if (node < n) {
            const float* p = &ep[nl2 * EPS + cg * 8];
            float4 v0 = *(const float4*)p;
            float4 v1 = *(const float4*)(p + 4);
            uint4 o;
            o.x = pack2(v0.x, v0.y);
            o.y = pack2(v0.z, v0.w);
            o.z = pack2(v1.x, v1.y);
            o.w = pack2(v1.z, v1.w);
            Zbf[(size_t)node * 5 + cg] = o;
        }
    }
}

// ---- one hop: acc = sum_{s->i} Zin[s] + Zin[i]; Zout = di^2 * acc.
// FINAL: fuse logits = Z2*dsq + b and log_softmax, write fp32 d_out.
// 5 lanes/node x uint4 (8 bf16); 51 nodes per 256-thread block.
template <bool FINAL>
__global__ __launch_bounds__(256) void prop_k(const int* __restrict__ rowptr,
                                              const int* __restrict__ col,
                                              const float* __restrict__ dinv,
                                              const float* __restrict__ dsq,
                                              const float* __restrict__ bias,
                                              const uint4* __restrict__ Zin,
                                              uint4* __restrict__ Zout_bf,
                                              float* __restrict__ out_f32, int n) {
    __shared__ float bsm[CDIM];
    __shared__ float red[256];
    int t = threadIdx.x;
    if (FINAL && t < CDIM) bsm[t] = bias[t];
    int g = t / 5;
    int c8 = t - g * 5;
    int node = blockIdx.x * NPB + g;
    bool active = (g < NPB) && (node < n);
    float acc[8];
    #pragma unroll
    for (int c = 0; c < 8; ++c) acc[c] = 0.f;
    float w = 0.f;
    if (active) {
        float di = dinv[node];
        w = di * di;
        addu4(Zin[(size_t)node * 5 + c8], acc);   // self-loop
        int e = rowptr[node];
        int end = rowptr[node + 1];
        for (; e + 3 < end; e += 4) {
            int s0 = col[e], s1 = col[e + 1], s2 = col[e + 2], s3 = col[e + 3];
            uint4 a0 = Zin[(size_t)s0 * 5 + c8];
            uint4 a1 = Zin[(size_t)s1 * 5 + c8];
            uint4 a2 = Zin[(size_t)s2 * 5 + c8];
            uint4 a3 = Zin[(size_t)s3 * 5 + c8];
            addu4(a0, acc); addu4(a1, acc); addu4(a2, acc); addu4(a3, acc);
        }
        for (; e < end; ++e)
            addu4(Zin[(size_t)col[e] * 5 + c8], acc);
    }

    if (!FINAL) {
        if (active) {
            uint4 o;
            o.x = pack2(acc[0] * w, acc[1] * w);
            o.y = pack2(acc[2] * w, acc[3] * w);
            o.z = pack2(acc[4] * w, acc[5] * w);
            o.w = pack2(acc[6] * w, acc[7] * w);
            Zout_bf[(size_t)node * 5 + c8] = o;
        }
        return;
    }

    // FINAL: logits + log_softmax via 5-lane LDS reduction.
    __syncthreads();  // bsm ready
    float v[8];
    float m8 = -INFINITY;
    if (active) {
        float ws_ = w * dsq[node];
        #pragma unroll
        for (int j = 0; j < 8; ++j) {
            v[j] = acc[j] * ws_ + bsm[c8 * 8 + j];
            m8 = fmaxf(m8, v[j]);
        }
    }
    red[t] = m8;
    __syncthreads();
    float m = m8;
    if (active) {
        int rb = g * 5;
        m = fmaxf(fmaxf(fmaxf(red[rb], red[rb + 1]), fmaxf(red[rb + 2], red[rb + 3])),
                  red[rb + 4]);
    }
    float s8 = 0.f;
    if (active) {
        #pragma unroll
        for (int j = 0; j < 8; ++j) s8 += expf(v[j] - m);
    }
    __syncthreads();
    red[t] = s8;
    __syncthreads();
    if (active) {
        int rb = g * 5;
        float s = (red[rb] + red[rb + 1]) + (red[rb + 2] + red[rb + 3]) + red[rb + 4];
        float ls = m + logf(s);
        float* p = out_f32 + (size_t)node * CDIM + c8 * 8;
        *(float4*)p = make_float4(v[0] - ls, v[1] - ls, v[2] - ls, v[3] - ls);
        *(float4*)(p + 4) = make_float4(v[4] - ls, v[5] - ls, v[6] - ls, v[7] - ls);
    }
}

extern "C" void kernel_launch(void* const* d_in, const int* in_sizes, int n_in,
                              void* d_out, int out_size, void* d_ws, size_t ws_size,
                              hipStream_t stream) {
    const float* x = (const float*)d_in[0];
    const float* W = (const float*)d_in[1];
    const float* b = (const float*)d_in[2];
    const int* ei = (const int*)d_in[3];

    int C = in_sizes[2];            // 40
    int F = in_sizes[1] / C;        // 128
    int N = in_sizes[0] / F;        // 100000
    int E = in_sizes[3] / 2;        // 1600000
    const int* src = ei;
    const int* dst = ei + E;

    // workspace: union region holds {G,T,bs,tmp} during build, then Z0bf (8MB).
    // Zb (hop-1 bf16 out, 8MB) separate: hop-2 gathers from it while writing
    // d_out, so it must not alias d_out. WF (24KB W fragments) separate:
    // written by wprep_k, read during gemm_k while Z0bf is being written.
    char* ws = (char*)d_ws;
    size_t goff = 0;
    int* G = (int*)(ws + goff);                       goff += (size_t)NBLK * NB * 4;
    int* T = (int*)(ws + goff);                       goff += (size_t)NB * 4;
    int* bs = (int*)(ws + goff);                      goff += (size_t)(NB + 1) * 4 + 12;
    goff = (goff + 15) & ~(size_t)15;
    unsigned int* tmp = (unsigned int*)(ws + goff);   goff += (size_t)E * 4;
    size_t z0bytes = (size_t)N * 80;                  // 5 x uint4 per node
    size_t unionEnd = (z0bytes > goff) ? z0bytes : goff;
    unionEnd = (unionEnd + 15) & ~(size_t)15;
    uint4* Z0bf = (uint4*)ws;        // overlays build scratch
    size_t off = unionEnd;
    int* rowptr = (int*)(ws + off); off += ((size_t)(N + 1) * 4 + 15) & ~(size_t)15;
    float* dinv = (float*)(ws + off); off += ((size_t)N * 4 + 15) & ~(size_t)15;
    float* dsq = (float*)(ws + off); off += ((size_t)N * 4 + 15) & ~(size_t)15;
    int* col = (int*)(ws + off); off += ((size_t)E * 4 + 15) & ~(size_t)15;
    uint4* Zb = (uint4*)(ws + off); off += (z0bytes + 15) & ~(size_t)15;
    uint4* WF = (uint4*)(ws + off); off += (size_t)2 * 768 * 16;

    int EB = (E + NBLK - 1) / NBLK;
    int NBr = (N + 255) >> BKT_SHIFT;

    hist_k<<<NBLK, 256, 0, stream>>>(dst, G, E, EB);
    colscan_k<<<NB, 256, 0, stream>>>(G, T);
    bscan_k<<<1, 256, 0, stream>>>(T, bs);
    part_k<<<NBLK, 256, 0, stream>>>(src, dst, G, bs, tmp, E, EB);
    csr_k<<<NBr, 256, 0, stream>>>(tmp, bs, rowptr, dinv, dsq, col, N, E);

    wprep_k<<<1, 256, 0, stream>>>(W, WF);
    gemm_k<<<(N + 63) / 64, 256, 0, stream>>>(x, WF, dinv, Z0bf, N);

    int pgrid = (N + NPB - 1) / NPB;
    prop_k<false><<<pgrid, 256, 0, stream>>>(rowptr, col, dinv, dsq, b,
                                             Z0bf, Zb, nullptr, N);
    prop_k<true><<<pgrid, 256, 0, stream>>>(rowptr, col, dinv, dsq, b,
                                            Zb, nullptr, (float*)d_out, N);
}

// Round 4
// 217.906 us; speedup vs baseline: 1.1398x; 1.0194x over previous
//
#include <hip/hip_runtime.h>
#include <math.h>

// SGC: out = log_softmax((A_hat^2 x) W + b), A_hat = D^-1/2 (A+I) D^-1/2
// (A^2 X) W == A^2 (X W): propagate in 40-dim class space.
// Z = D^-1/2 Y: Z' = di^2 (sum_s Z_s + Z_i) -> pure gather-add.
// Gathered Z buffers bf16 (80 B rows = 2 lines/edge, 8 MB footprint).
// Round-11 (kept): MFMA gemm_k, split-bf16 (x=xh+xl, W=Wh+Wl; 3 MFMAs),
// A frags straight from global, W frags pre-swizzled by wprep_k. Landed:
// gemm left the top-5 (<41us fill threshold), absmax unchanged.
// Round-12: prop_k two-team split. Arithmetic says prop is latency-bound:
// VALU ~3us, cache traffic ~205MB ~10us, yet ~35-40us/hop -> serial chain
// of deg/4 quad-iterations on random 16B gathers dominates. Now 10 lanes
// per node (2 teams x 5 c8-lanes), teams take alternating edge-quads ->
// chain halves, 8 loads in flight/node, divergence maxdeg ~halves. Teams
// merge via 4KB LDS + one barrier. 25 nodes per 256-thr block, grid 4000.

#define FDIM 128
#define CDIM 40
#define C4   10
#define BKT_SHIFT 8
#define NB   512   // bucket slots (>= ceil(N/256))
#define NBLK 512   // edge-partition blocks
#define NPB  25    // nodes per 256-thread prop block (10 lanes/node, 2 teams)

typedef __attribute__((ext_vector_type(4))) float floatx4;
typedef __attribute__((ext_vector_type(8))) short bshort8;

// ---------- bf16 helpers (RTNE pack; finite inputs) ----------
__device__ __forceinline__ unsigned int bf16rn(float f) {
    unsigned int u = __float_as_uint(f);
    return (u + 0x7fffu + ((u >> 16) & 1u)) >> 16;
}
__device__ __forceinline__ unsigned int pack2(float lo, float hi) {
    unsigned int a = bf16rn(lo);
    unsigned int b = __float_as_uint(hi);
    b = (b + 0x7fffu + ((b >> 16) & 1u)) & 0xffff0000u;
    return a | b;
}
__device__ __forceinline__ void addu4(uint4 u, float* a) {
    a[0] += __uint_as_float(u.x << 16);
    a[1] += __uint_as_float(u.x & 0xffff0000u);
    a[2] += __uint_as_float(u.y << 16);
    a[3] += __uint_as_float(u.y & 0xffff0000u);
    a[4] += __uint_as_float(u.z << 16);
    a[5] += __uint_as_float(u.z & 0xffff0000u);
    a[6] += __uint_as_float(u.w << 16);
    a[7] += __uint_as_float(u.w & 0xffff0000u);
}

// ---- pass 1: per-block histogram over dst buckets (LDS, no global atomics)
__global__ void hist_k(const int* __restrict__ dst, int* __restrict__ G,
                       int E, int EB) {
    __shared__ int h[NB];
    int t = threadIdx.x;
    for (int i = t; i < NB; i += 256) h[i] = 0;
    __syncthreads();
    int s = blockIdx.x * EB;
    int e = min(s + EB, E);
    for (int i = s + t; i < e; i += 256)
        atomicAdd(&h[dst[i] >> BKT_SHIFT], 1);
    __syncthreads();
    for (int i = t; i < NB; i += 256) G[blockIdx.x * NB + i] = h[i];
}

// ---- pass 2: per-bucket exclusive scan over blocks (in-place on G); totals->T
__global__ void colscan_k(int* __restrict__ G, int* __restrict__ T) {
    __shared__ int lds[256];
    int j = blockIdx.x;
    int t = threadIdx.x;
    int v0 = G[(2 * t) * NB + j];
    int v1 = G[(2 * t + 1) * NB + j];
    int s = v0 + v1;
    lds[t] = s;
    __syncthreads();
    for (int off = 1; off < 256; off <<= 1) {
        int a = (t >= off) ? lds[t - off] : 0;
        __syncthreads();
        lds[t] += a;
        __syncthreads();
    }
    int excl = lds[t] - s;
    G[(2 * t) * NB + j] = excl;
    G[(2 * t + 1) * NB + j] = excl + v0;
    if (t == 255) T[j] = lds[255];
}

// ---- pass 2b: exclusive scan of bucket totals -> bs[0..NB], bs[NB]=E
__global__ void bscan_k(const int* __restrict__ T, int* __restrict__ bs) {
    __shared__ int lds[256];
    int t = threadIdx.x;
    int v0 = T[2 * t];
    int v1 = T[2 * t + 1];
    int s = v0 + v1;
    lds[t] = s;
    __syncthreads();
    for (int off = 1; off < 256; off <<= 1) {
        int a = (t >= off) ? lds[t - off] : 0;
        __syncthreads();
        lds[t] += a;
        __syncthreads();
    }
    int excl = lds[t] - s;
    bs[2 * t] = excl;
    bs[2 * t + 1] = excl + v0;
    if (t == 255) bs[NB] = lds[255];
}

// ---- pass 3: scatter packed edges into bucket-partitioned tmp
// pack: src (24 bits) | dstLocal (8 bits) << 24   [requires N < 2^24]
__global__ void part_k(const int* __restrict__ src, const int* __restrict__ dst,
                       const int* __restrict__ G, const int* __restrict__ bs,
                       unsigned int* __restrict__ tmp, int E, int EB) {
    __shared__ int offs[NB];
    __shared__ int cur[NB];
    int t = threadIdx.x;
    for (int i = t; i < NB; i += 256) {
        offs[i] = bs[i] + G[blockIdx.x * NB + i];
        cur[i] = 0;
    }
    __syncthreads();
    int s = blockIdx.x * EB;
    int e = min(s + EB, E);
    for (int i = s + t; i < e; i += 256) {
        int d = dst[i];
        int j = d >> BKT_SHIFT;
        int r = atomicAdd(&cur[j], 1);
        tmp[offs[j] + r] = (unsigned int)src[i] | ((unsigned int)(d & 255) << 24);
    }
}

// ---- pass 4: one block per bucket: rowptr/dinv/dsq + CSR col fill (all local)
__global__ void csr_k(const unsigned int* __restrict__ tmp, const int* __restrict__ bs,
                      int* __restrict__ rowptr, float* __restrict__ dinv,
                      float* __restrict__ dsq, int* __restrict__ col, int N, int E) {
    __shared__ int cnt[256];
    __shared__ int ptr[256];
    int j = blockIdx.x;
    int t = threadIdx.x;
    int base = j << BKT_SHIFT;
    int s = bs[j];
    int e = bs[j + 1];
    cnt[t] = 0;
    __syncthreads();
    for (int i = s + t; i < e; i += 256)
        atomicAdd(&cnt[tmp[i] >> 24], 1);
    __syncthreads();
    int v = cnt[t];
    ptr[t] = v;
    __syncthreads();
    for (int off = 1; off < 256; off <<= 1) {
        int a = (t >= off) ? ptr[t - off] : 0;
        __syncthreads();
        ptr[t] += a;
        __syncthreads();
    }
    int excl = ptr[t] - v;
    int node = base + t;
    if (node < N) {
        rowptr[node] = s + excl;
        float d = (float)(v + 1);              // +1 self-loop
        dinv[node] = rsqrtf(d);
        dsq[node] = sqrtf(d);
    }
    if (j == 0 && t == 0) rowptr[N] = E;
    cnt[t] = excl;  // cursor
    __syncthreads();
    for (int i = s + t; i < e; i += 256) {
        unsigned int p = tmp[i];
        int loc = p >> 24;
        int r = atomicAdd(&cnt[loc], 1);
        col[s + r] = (int)(p & 0xFFFFFF);
    }
}

// ---- W fragment prep (once): split-bf16 W into MFMA B-fragment order.
// B frag for mfma_f32_16x16x32_bf16: lane l holds B[k = 8*(l>>4)+j][n = l&15].
// WF[(nt*4+ch)*64 + l] = hi frag, WF[768 + ...] = lo frag (uint4 = 8 bf16).
// k_global = ch*32 + 8*(l>>4) + j ; class = nt*16 + (l&15), 0 if >= CDIM.
__global__ __launch_bounds__(256) void wprep_k(const float* __restrict__ W,
                                               uint4* __restrict__ WF) {
    int t = threadIdx.x;
    for (int s = t; s < 768; s += 256) {
        int l = s & 63;
        int g = s >> 6;           // 0..11: nt = g>>2, ch = g&3
        int nt = g >> 2;
        int ch = g & 3;
        int c = nt * 16 + (l & 15);
        int kb = ch * 32 + ((l >> 4) << 3);
        unsigned int hw[4], lw[4];
        #pragma unroll
        for (int jw = 0; jw < 4; ++jw) {
            unsigned int hs[2], ls[2];
            #pragma unroll
            for (int e = 0; e < 2; ++e) {
                int j = jw * 2 + e;
                float w = (c < CDIM) ? W[(kb + j) * CDIM + c] : 0.f;
                unsigned int u = __float_as_uint(w);
                float wh = __uint_as_float(u & 0xffff0000u);
                float wr = w - wh;
                hs[e] = u >> 16;
                ls[e] = __float_as_uint(wr) >> 16;
            }
            hw[jw] = hs[0] | (hs[1] << 16);
            lw[jw] = ls[0] | (ls[1] << 16);
        }
        WF[g * 64 + l] = make_uint4(hw[0], hw[1], hw[2], hw[3]);
        WF[768 + g * 64 + l] = make_uint4(lw[0], lw[1], lw[2], lw[3]);
    }
}

// ---- Z0[node][40] (bf16) = dinv[node] * (x[node] @ W)  -- MFMA version.
// Block = 256 thr = 4 waves; wave w owns nodes [blk*64 + 16w, +16), all 40
// classes as 3 N-tiles of 16. A frag (lane l: row l&15, k=8*(l>>4)+j) loads
// straight from global x: per instr 16 rows x 64B contiguous = coalesced.
// 3 MFMAs per (nt,ch): xh*Wh + xl*Wh + xh*Wl. Epilogue transposes D frags
// (row = 4*(l>>4)+reg, col = l&15) through 13KB LDS into packed bf16 rows.
__device__ __forceinline__ void split8(const float* p, bshort8& hi, bshort8& lo) {
    float4 a = *(const float4*)p;
    float4 b = *(const float4*)(p + 4);
    float f[8] = {a.x, a.y, a.z, a.w, b.x, b.y, b.z, b.w};
    #pragma unroll
    for (int j = 0; j < 8; ++j) {
        unsigned int u = __float_as_uint(f[j]);
        float r = f[j] - __uint_as_float(u & 0xffff0000u);
        hi[j] = (short)(u >> 16);
        lo[j] = (short)(__float_as_uint(r) >> 16);
    }
}

#define EPS 52   // epilogue LDS row stride (floats): 16B-aligned, lg 2-way only

__global__ __launch_bounds__(256) void gemm_k(const float* __restrict__ x,
                                              const uint4* __restrict__ WF,
                                              const float* __restrict__ dinv,
                                              uint4* __restrict__ Zbf, int n) {
    __shared__ float ep[64 * EPS];   // 13.3 KB
    int t = threadIdx.x;
    int wid = t >> 6;
    int l = t & 63;
    int lr = l & 15;
    int lg = l >> 4;
    int base64 = blockIdx.x * 64;
    int mbase = base64 + wid * 16;
    int node_a = mbase + lr;
    bool arow_ok = node_a < n;
    const bshort8* WFv = (const bshort8*)WF;

    floatx4 acc0 = {0.f, 0.f, 0.f, 0.f};
    floatx4 acc1 = {0.f, 0.f, 0.f, 0.f};
    floatx4 acc2 = {0.f, 0.f, 0.f, 0.f};

    #pragma unroll
    for (int ch = 0; ch < 4; ++ch) {
        bshort8 ah, al;
        if (arow_ok) {
            split8(x + (size_t)node_a * FDIM + ch * 32 + lg * 8, ah, al);
        } else {
            #pragma unroll
            for (int j = 0; j < 8; ++j) { ah[j] = 0; al[j] = 0; }
        }
        bshort8 bh0 = WFv[(0 * 4 + ch) * 64 + l];
        bshort8 bl0 = WFv[768 + (0 * 4 + ch) * 64 + l];
        bshort8 bh1 = WFv[(1 * 4 + ch) * 64 + l];
        bshort8 bl1 = WFv[768 + (1 * 4 + ch) * 64 + l];
        bshort8 bh2 = WFv[(2 * 4 + ch) * 64 + l];
        bshort8 bl2 = WFv[768 + (2 * 4 + ch) * 64 + l];
        acc0 = __builtin_amdgcn_mfma_f32_16x16x32_bf16(ah, bh0, acc0, 0, 0, 0);
        acc0 = __builtin_amdgcn_mfma_f32_16x16x32_bf16(al, bh0, acc0, 0, 0, 0);
        acc0 = __builtin_amdgcn_mfma_f32_16x16x32_bf16(ah, bl0, acc0, 0, 0, 0);
        acc1 = __builtin_amdgcn_mfma_f32_16x16x32_bf16(ah, bh1, acc1, 0, 0, 0);
        acc1 = __builtin_amdgcn_mfma_f32_16x16x32_bf16(al, bh1, acc1, 0, 0, 0);
        acc1 = __builtin_amdgcn_mfma_f32_16x16x32_bf16(ah, bl1, acc1, 0, 0, 0);
        acc2 = __builtin_amdgcn_mfma_f32_16x16x32_bf16(ah, bh2, acc2, 0, 0, 0);
        acc2 = __builtin_amdgcn_mfma_f32_16x16x32_bf16(al, bh2, acc2, 0, 0, 0);
        acc2 = __builtin_amdgcn_mfma_f32_16x16x32_bf16(ah, bl2, acc2, 0, 0, 0);
    }

    // epilogue: D lane l reg r -> node mbase + 4*lg + r, class nt*16 + lr.
    int nlb = wid * 16 + 4 * lg;
    #pragma unroll
    for (int r = 0; r < 4; ++r) {
        int nd = mbase + 4 * lg + r;
        float di = (nd < n) ? dinv[nd] : 0.f;
        ep[(nlb + r) * EPS + 0 * 16 + lr] = acc0[r] * di;
        ep[(nlb + r) * EPS + 1 * 16 + lr] = acc1[r] * di;
        ep[(nlb + r) * EPS + 2 * 16 + lr] = acc2[r] * di;
    }
    __syncthreads();
    for (int i = t; i < 320; i += 256) {
        int nl2 = i / 5;
        int cg = i - nl2 * 5;
        int node = base64 + nl2;
        if (node < n) {
            const float* p = &ep[nl2 * EPS + cg * 8];
            float4 v0 = *(const float4*)p;
            float4 v1 = *(const float4*)(p + 4);
            uint4 o;
            o.x = pack2(v0.x, v0.y);
            o.y = pack2(v0.z, v0.w);
            o.z = pack2(v1.x, v1.y);
            o.w = pack2(v1.z, v1.w);
            Zbf[(size_t)node * 5 + cg] = o;
        }
    }
}

// ---- one hop: acc = sum_{s->i} Zin[s] + Zin[i]; Zout = di^2 * acc.
// FINAL: fuse logits = Z2*dsq + b and log_softmax, write fp32 d_out.
// Round-12: 10 lanes/node = 2 teams x 5 c8-lanes; teams take alternating
// quads of 4 edges (team tm starts at e0 + 4*tm, strides 8). Serial gather
// chain per lane halves; 8 loads in flight per node. Teams merge partials
// via LDS (pr) + one barrier; only team-0 lanes produce output / softmax.
template <bool FINAL>
__global__ __launch_bounds__(256) void prop_k(const int* __restrict__ rowptr,
                                              const int* __restrict__ col,
                                              const float* __restrict__ dinv,
                                              const float* __restrict__ dsq,
                                              const float* __restrict__ bias,
                                              const uint4* __restrict__ Zin,
                                              uint4* __restrict__ Zout_bf,
                                              float* __restrict__ out_f32, int n) {
    __shared__ float bsm[CDIM];
    __shared__ float red[256];
    __shared__ float pr[NPB * 5 * 8];   // team-1 partials, 4 KB
    int t = threadIdx.x;
    if (FINAL && t < CDIM) bsm[t] = bias[t];
    int g = t / 10;
    int r = t - g * 10;
    int team = r / 5;           // 0 or 1
    int c8 = r - team * 5;      // 0..4
    int node = blockIdx.x * NPB + g;
    bool active = (g < NPB) && (node < n);
    float acc[8];
    #pragma unroll
    for (int c = 0; c < 8; ++c) acc[c] = 0.f;
    float w = 0.f;
    if (active) {
        float di = dinv[node];
        w = di * di;
        if (team == 0) addu4(Zin[(size_t)node * 5 + c8], acc);   // self-loop
        int end = rowptr[node + 1];
        int e = rowptr[node] + team * 4;
        for (; e + 3 < end; e += 8) {       // this team's full quads
            int s0 = col[e], s1 = col[e + 1], s2 = col[e + 2], s3 = col[e + 3];
            uint4 a0 = Zin[(size_t)s0 * 5 + c8];
            uint4 a1 = Zin[(size_t)s1 * 5 + c8];
            uint4 a2 = Zin[(size_t)s2 * 5 + c8];
            uint4 a3 = Zin[(size_t)s3 * 5 + c8];
            addu4(a0, acc); addu4(a1, acc); addu4(a2, acc); addu4(a3, acc);
        }
        for (; e < end; ++e)                // this team's tail (<=3 edges)
            addu4(Zin[(size_t)col[e] * 5 + c8], acc);
    }

    // merge team-1 partials into team-0 accumulators.
    if (active && team == 1) {
        float* p = &pr[(g * 5 + c8) * 8];
        #pragma unroll
        for (int j = 0; j < 8; ++j) p[j] = acc[j];
    }
    __syncthreads();   // also publishes bsm for FINAL
    if (active && team == 0) {
        const float* p = &pr[(g * 5 + c8) * 8];
        #pragma unroll
        for (int j = 0; j < 8; ++j) acc[j] += p[j];
    }

    if (!FINAL) {
        if (active && team == 0) {
            uint4 o;
            o.x = pack2(acc[0] * w, acc[1] * w);
            o.y = pack2(acc[2] * w, acc[3] * w);
            o.z = pack2(acc[4] * w, acc[5] * w);
            o.w = pack2(acc[6] * w, acc[7] * w);
            Zout_bf[(size_t)node * 5 + c8] = o;
        }
        return;
    }

    // FINAL: logits + log_softmax; reduce over the 5 team-0 lanes of each
    // node (team-1 red slots hold -INF / 0 and are never read).
    float v[8];
    float m8 = -INFINITY;
    if (active && team == 0) {
        float ws_ = w * dsq[node];
        #pragma unroll
        for (int j = 0; j < 8; ++j) {
            v[j] = acc[j] * ws_ + bsm[c8 * 8 + j];
            m8 = fmaxf(m8, v[j]);
        }
    }
    red[t] = m8;
    __syncthreads();
    float m = m8;
    if (active && team == 0) {
        int rb = g * 10;
        m = fmaxf(fmaxf(fmaxf(red[rb], red[rb + 1]), fmaxf(red[rb + 2], red[rb + 3])),
                  red[rb + 4]);
    }
    float s8 = 0.f;
    if (active && team == 0) {
        #pragma unroll
        for (int j = 0; j < 8; ++j) s8 += expf(v[j] - m);
    }
    __syncthreads();
    red[t] = s8;
    __syncthreads();
    if (active && team == 0) {
        int rb = g * 10;
        float s = (red[rb] + red[rb + 1]) + (red[rb + 2] + red[rb + 3]) + red[rb + 4];
        float ls = m + logf(s);
        float* p = out_f32 + (size_t)node * CDIM + c8 * 8;
        *(float4*)p = make_float4(v[0] - ls, v[1] - ls, v[2] - ls, v[3] - ls);
        *(float4*)(p + 4) = make_float4(v[4] - ls, v[5] - ls, v[6] - ls, v[7] - ls);
    }
}

extern "C" void kernel_launch(void* const* d_in, const int* in_sizes, int n_in,
                              void* d_out, int out_size, void* d_ws, size_t ws_size,
                              hipStream_t stream) {
    const float* x = (const float*)d_in[0];
    const float* W = (const float*)d_in[1];
    const float* b = (const float*)d_in[2];
    const int* ei = (const int*)d_in[3];

    int C = in_sizes[2];            // 40
    int F = in_sizes[1] / C;        // 128
    int N = in_sizes[0] / F;        // 100000
    int E = in_sizes[3] / 2;        // 1600000
    const int* src = ei;
    const int* dst = ei + E;

    // workspace: union region holds {G,T,bs,tmp} during build, then Z0bf (8MB).
    // Zb (hop-1 bf16 out, 8MB) separate: hop-2 gathers from it while writing
    // d_out, so it must not alias d_out. WF (24KB W fragments) separate:
    // written by wprep_k, read during gemm_k while Z0bf is being written.
    char* ws = (char*)d_ws;
    size_t goff = 0;
    int* G = (int*)(ws + goff);                       goff += (size_t)NBLK * NB * 4;
    int* T = (int*)(ws + goff);                       goff += (size_t)NB * 4;
    int* bs = (int*)(ws + goff);                      goff += (size_t)(NB + 1) * 4 + 12;
    goff = (goff + 15) & ~(size_t)15;
    unsigned int* tmp = (unsigned int*)(ws + goff);   goff += (size_t)E * 4;
    size_t z0bytes = (size_t)N * 80;                  // 5 x uint4 per node
    size_t unionEnd = (z0bytes > goff) ? z0bytes : goff;
    unionEnd = (unionEnd + 15) & ~(size_t)15;
    uint4* Z0bf = (uint4*)ws;        // overlays build scratch
    size_t off = unionEnd;
    int* rowptr = (int*)(ws + off); off += ((size_t)(N + 1) * 4 + 15) & ~(size_t)15;
    float* dinv = (float*)(ws + off); off += ((size_t)N * 4 + 15) & ~(size_t)15;
    float* dsq = (float*)(ws + off); off += ((size_t)N * 4 + 15) & ~(size_t)15;
    int* col = (int*)(ws + off); off += ((size_t)E * 4 + 15) & ~(size_t)15;
    uint4* Zb = (uint4*)(ws + off); off += (z0bytes + 15) & ~(size_t)15;
    uint4* WF = (uint4*)(ws + off); off += (size_t)2 * 768 * 16;

    int EB = (E + NBLK - 1) / NBLK;
    int NBr = (N + 255) >> BKT_SHIFT;

    hist_k<<<NBLK, 256, 0, stream>>>(dst, G, E, EB);
    colscan_k<<<NB, 256, 0, stream>>>(G, T);
    bscan_k<<<1, 256, 0, stream>>>(T, bs);
    part_k<<<NBLK, 256, 0, stream>>>(src, dst, G, bs, tmp, E, EB);
    csr_k<<<NBr, 256, 0, stream>>>(tmp, bs, rowptr, dinv, dsq, col, N, E);

    wprep_k<<<1, 256, 0, stream>>>(W, WF);
    gemm_k<<<(N + 63) / 64, 256, 0, stream>>>(x, WF, dinv, Z0bf, N);

    int pgrid = (N + NPB - 1) / NPB;
    prop_k<false><<<pgrid, 256, 0, stream>>>(rowptr, col, dinv, dsq, b,
                                             Z0bf, Zb, nullptr, N);
    prop_k<true><<<pgrid, 256, 0, stream>>>(rowptr, col, dinv, dsq, b,
                                            Zb, nullptr, (float*)d_out, N);
}